// Round 7
// baseline (333.884 us; speedup 1.0000x reference)
//
#include <hip/hip_runtime.h>
#include <stdint.h>

#define DIM 768
#define NH 12
#define HD 64
#define BSZ 4
#define SEQ 2048
#define MROWS (BSZ*SEQ)   // 8192

typedef __attribute__((ext_vector_type(8))) short v8s;        // 8 bf16 (4 VGPRs)
typedef __attribute__((ext_vector_type(4))) float v4f;        // 4 fp32 acc
typedef __attribute__((ext_vector_type(8))) _Float16 v8h;     // 8 f16 (4 VGPRs)
typedef __attribute__((ext_vector_type(2))) __fp16 v2fp;      // cvt_pkrtz native type

__device__ __forceinline__ uint16_t f2bf(float x) {
  union { float f; uint32_t u; } v; v.f = x;
  uint32_t r = v.u + 0x7fffu + ((v.u >> 16) & 1u);   // RNE
  return (uint16_t)(r >> 16);
}

#if __has_builtin(__builtin_amdgcn_cvt_pk_bf16_f32)
typedef __attribute__((ext_vector_type(2))) __bf16 v2bf;
__device__ __forceinline__ uint32_t pack_bf16(float a, float b) {
  union { v2bf v; uint32_t u; } c;
  c.v = __builtin_amdgcn_cvt_pk_bf16_f32(a, b);
  return c.u;
}
#else
__device__ __forceinline__ uint32_t pack_bf16(float a, float b) {
  return (uint32_t)f2bf(a) | ((uint32_t)f2bf(b) << 16);
}
#endif

__device__ __forceinline__ uint32_t pack_f16(float a, float b) {
#if __has_builtin(__builtin_amdgcn_cvt_pkrtz)
  union { v2fp h; uint32_t u; } c;
  c.h = __builtin_amdgcn_cvt_pkrtz(a, b);
  return c.u;
#else
  union { _Float16 h[2]; uint32_t u; } c;
  c.h[0] = (_Float16)a; c.h[1] = (_Float16)b; return c.u;
#endif
}

__device__ __forceinline__ float fexp2(float x) {
#if __has_builtin(__builtin_amdgcn_exp2f)
  return __builtin_amdgcn_exp2f(x);
#else
  return exp2f(x);
#endif
}

// sign-extended 1-bit extract: returns 0 or 0xFFFFFFFF
__device__ __forceinline__ int sbfe1(uint32_t w, int off) {
#if __has_builtin(__builtin_amdgcn_sbfe)
  return __builtin_amdgcn_sbfe((int)w, off, 1);
#else
  return ((int)(w << (31 - off))) >> 31;
#endif
}
__device__ __forceinline__ float maskf(float x, int mext) {
  union { float f; int i; } u; u.f = x; u.i &= mext; return u.f;
}

// async global->LDS, 16B per lane; LDS dst = wave-uniform base + lane*16
__device__ __forceinline__ void gl16(const void* g, void* l) {
  __builtin_amdgcn_global_load_lds(
      (const __attribute__((address_space(1))) unsigned int*)g,
      (__attribute__((address_space(3))) unsigned int*)l, 16, 0, 0);
}

// ---------------- pre-pass: fp32 -> bf16 (both X tensors, one launch) ----------
__global__ void cvt_bf16_kernel(const float* __restrict__ src0, uint16_t* __restrict__ dst0,
                                const float* __restrict__ src1, uint16_t* __restrict__ dst1,
                                int n4) {
  int i = blockIdx.x * blockDim.x + threadIdx.x;
  const float* src = (i < n4) ? src0 : src1;
  uint16_t* dst = (i < n4) ? dst0 : dst1;
  int j = (i < n4) ? i : i - n4;
  float4 v = ((const float4*)src)[j];
  ushort4 o;
  o.x = f2bf(v.x); o.y = f2bf(v.y); o.z = f2bf(v.z); o.w = f2bf(v.w);
  ((ushort4*)dst)[j] = o;
}

// ---------------- pre-pass: mask int32 -> u64 bitmask [b][kt][q] ----------------
__global__ void mask_bits_kernel(const int* __restrict__ src,
                                 unsigned long long* __restrict__ dst, int nwords) {
  int gtid = blockIdx.x * blockDim.x + threadIdx.x;
  int w = gtid >> 6;
  int lane = threadIdx.x & 63;
  if (w >= nwords) return;
  int b  = w >> 16;
  int q  = (w >> 5) & 2047;
  int kt = w & 31;
  int m = src[((size_t)b * SEQ + q) * SEQ + kt * 64 + lane];
  unsigned long long bits = __ballot(m != 0);
  if (lane == 0) dst[((size_t)b * 32 + kt) * SEQ + q] = bits;
}

// ---------------- pre-pass: W [K][N] fp32 -> WT [N][K] bf16 ----------------
__global__ void wtrans_kernel(const float* __restrict__ Wq, const float* __restrict__ Wk,
                              const float* __restrict__ Wv, const float* __restrict__ Wo,
                              uint16_t* __restrict__ WT) {
  __shared__ float tile[32][33];
  int z = blockIdx.z;
  const float* src = (z==0) ? Wq : (z==1) ? Wk : (z==2) ? Wv : Wo;
  uint16_t* dst = WT + (size_t)z * DIM * DIM;
  int tx = threadIdx.x, ty = threadIdx.y;
  int x  = blockIdx.x * 32 + tx;
  int y0 = blockIdx.y * 32;
  for (int j = ty; j < 32; j += 8)
    tile[j][tx] = src[(size_t)(y0 + j) * DIM + x];
  __syncthreads();
  int xo = y0 + tx;
  for (int j = ty; j < 32; j += 8)
    dst[(size_t)(blockIdx.x * 32 + j) * DIM + xo] = f2bf(tile[tx][j]);
}

// ---------------- GEMM-T (modes 0,1,3): C^T orientation for vector stores ------
// mfma(bfr, af): C rows = n (quad*4+r), cols = m (lr) -> each lane holds 4
// consecutive n/d for one m -> b64 (bf16) / b128 (fp32) epilogue stores.
// mode 0: Q -> Qw [b,h,s,d]*(SCALE*log2e)  mode 1: K -> Kw (d-chunk swz by s&7)
// mode 3: O -> d_out fp32 [m,n]
__global__ __launch_bounds__(256) void gemm_t_kernel(
    const uint16_t* __restrict__ Xf, const uint16_t* __restrict__ Xt,
    const uint16_t* __restrict__ WT, const uint16_t* __restrict__ AO,
    const float* __restrict__ bq, const float* __restrict__ bk,
    const float* __restrict__ bo,
    uint16_t* __restrict__ Qw, uint16_t* __restrict__ Kw,
    float* __restrict__ Out, int mode_base)
{
  __shared__ alignas(16) uint16_t As[128 * 32];
  __shared__ alignas(16) uint16_t Bs[128 * 32];
  int mode = mode_base + blockIdx.z;
  const uint16_t* A = (mode == 0) ? Xf : (mode == 3 ? AO : Xt);
  const uint16_t* W = WT + (size_t)mode * DIM * DIM;
  const float* bias = (mode == 0) ? bq : (mode == 1) ? bk : bo;

  int m0 = blockIdx.x * 128, n0 = blockIdx.y * 128;
  int tid = threadIdx.x;
  int wave = tid >> 6, lane = tid & 63, lr = lane & 15, quad = lane >> 4;
  int wm = (wave >> 1) * 64, wn = (wave & 1) * 64;

  int seg = (lane & 3) ^ ((lane >> 3) & 3);
  const uint16_t* agl = A + (size_t)(m0 + wave * 32 + (lane >> 2)) * DIM + seg * 8;
  const uint16_t* bgl = W + (size_t)(n0 + wave * 32 + (lane >> 2)) * DIM + seg * 8;
  int lb = wave * 1024;
  int ck = (lr >> 1) & 3;

  v4f acc[4][4];            // [n-tile][m-tile]
  v4f vz = {0.f, 0.f, 0.f, 0.f};
  #pragma unroll
  for (int j = 0; j < 4; j++)
    #pragma unroll
    for (int i = 0; i < 4; i++) acc[j][i] = vz;

  for (int k0 = 0; k0 < DIM; k0 += 32) {
    __syncthreads();
    gl16(agl + k0,            &As[lb]);
    gl16(agl + k0 + 16 * DIM, &As[lb + 512]);
    gl16(bgl + k0,            &Bs[lb]);
    gl16(bgl + k0 + 16 * DIM, &Bs[lb + 512]);
    __syncthreads();
    v8s af[4], bfr[4];
    #pragma unroll
    for (int i = 0; i < 4; i++)
      af[i] = *(const v8s*)&As[(wm + i * 16 + lr) * 32 + ((quad ^ ck) << 3)];
    #pragma unroll
    for (int j = 0; j < 4; j++)
      bfr[j] = *(const v8s*)&Bs[(wn + j * 16 + lr) * 32 + ((quad ^ ck) << 3)];
    #pragma unroll
    for (int j = 0; j < 4; j++)
      #pragma unroll
      for (int i = 0; i < 4; i++)
        acc[j][i] = __builtin_amdgcn_mfma_f32_16x16x32_bf16(bfr[j], af[i], acc[j][i], 0, 0, 0);
  }

  #pragma unroll
  for (int j = 0; j < 4; j++) {
    int nb = n0 + wn + j * 16 + quad * 4;
    float4 bj4 = *(const float4*)&bias[nb];
    #pragma unroll
    for (int i = 0; i < 4; i++) {
      int m = m0 + wm + i * 16 + lr;
      float v0 = acc[j][i][0] + bj4.x;
      float v1 = acc[j][i][1] + bj4.y;
      float v2 = acc[j][i][2] + bj4.z;
      float v3 = acc[j][i][3] + bj4.w;
      if (mode == 3) {
        float4 o = {v0, v1, v2, v3};
        *(float4*)&Out[(size_t)m * DIM + nb] = o;
      } else {
        if (mode == 0) {
          v0 *= 0.18033688f; v1 *= 0.18033688f;   // HD^-0.5 * log2(e)
          v2 *= 0.18033688f; v3 *= 0.18033688f;
        }
        int h = nb >> 6, d = nb & 63;
        int b = m >> 11, s = m & 2047;
        int dd = (mode == 1) ? ((((d >> 3) ^ (s & 7)) << 3) + (d & 7)) : d;
        uint2 pk;
        pk.x = pack_bf16(v0, v1);
        pk.y = pack_bf16(v2, v3);
        uint16_t* Dst = (mode == 0) ? Qw : Kw;
        *(uint2*)&Dst[((size_t)(b * NH + h) * SEQ + s) * HD + dd] = pk;
      }
    }
  }
}

// ---------------- GEMM-V (mode 2): natural orientation, s-consecutive stores ---
// V -> Vw [b,h,d,s] f16, kk pair-permuted + 16B-chunk swz by d&7
__global__ __launch_bounds__(256) void gemm_v_kernel(
    const uint16_t* __restrict__ Xt, const uint16_t* __restrict__ WT,
    const float* __restrict__ bv, uint16_t* __restrict__ Vw)
{
  __shared__ alignas(16) uint16_t As[128 * 32];
  __shared__ alignas(16) uint16_t Bs[128 * 32];
  const uint16_t* A = Xt;
  const uint16_t* W = WT + (size_t)2 * DIM * DIM;

  int m0 = blockIdx.x * 128, n0 = blockIdx.y * 128;
  int tid = threadIdx.x;
  int wave = tid >> 6, lane = tid & 63, lr = lane & 15, quad = lane >> 4;
  int wm = (wave >> 1) * 64, wn = (wave & 1) * 64;

  int seg = (lane & 3) ^ ((lane >> 3) & 3);
  const uint16_t* agl = A + (size_t)(m0 + wave * 32 + (lane >> 2)) * DIM + seg * 8;
  const uint16_t* bgl = W + (size_t)(n0 + wave * 32 + (lane >> 2)) * DIM + seg * 8;
  int lb = wave * 1024;
  int ck = (lr >> 1) & 3;

  v4f acc[4][4];
  v4f vz = {0.f, 0.f, 0.f, 0.f};
  #pragma unroll
  for (int i = 0; i < 4; i++)
    #pragma unroll
    for (int j = 0; j < 4; j++) acc[i][j] = vz;

  for (int k0 = 0; k0 < DIM; k0 += 32) {
    __syncthreads();
    gl16(agl + k0,            &As[lb]);
    gl16(agl + k0 + 16 * DIM, &As[lb + 512]);
    gl16(bgl + k0,            &Bs[lb]);
    gl16(bgl + k0 + 16 * DIM, &Bs[lb + 512]);
    __syncthreads();
    v8s af[4], bfr[4];
    #pragma unroll
    for (int i = 0; i < 4; i++)
      af[i] = *(const v8s*)&As[(wm + i * 16 + lr) * 32 + ((quad ^ ck) << 3)];
    #pragma unroll
    for (int j = 0; j < 4; j++)
      bfr[j] = *(const v8s*)&Bs[(wn + j * 16 + lr) * 32 + ((quad ^ ck) << 3)];
    #pragma unroll
    for (int i = 0; i < 4; i++)
      #pragma unroll
      for (int j = 0; j < 4; j++)
        acc[i][j] = __builtin_amdgcn_mfma_f32_16x16x32_bf16(af[i], bfr[j], acc[i][j], 0, 0, 0);
  }

  float bj[4];
  #pragma unroll
  for (int j = 0; j < 4; j++) bj[j] = bv[n0 + wn + j * 16 + lr];

  // kk = s&63; pos = pair*32 + quadk*8 + (nt&1)*4 + j, chunk XOR-swz by d&7
  #pragma unroll
  for (int i = 0; i < 4; i++) {
    int m = m0 + wm + i * 16 + quad * 4;
    int b = m >> 11, s0 = m & 2047;
    int kk0 = s0 & 63;
    int pos = (kk0 >> 5) * 32 + ((kk0 >> 2) & 3) * 8 + ((kk0 >> 4) & 1) * 4;
    int chunk = pos >> 3, off = pos & 7;
    #pragma unroll
    for (int j = 0; j < 4; j++) {
      int n = n0 + wn + j * 16 + lr;
      int h = n >> 6, d = n & 63;
      uint2 pk;
      pk.x = pack_f16(acc[i][j][0] + bj[j], acc[i][j][1] + bj[j]);
      pk.y = pack_f16(acc[i][j][2] + bj[j], acc[i][j][3] + bj[j]);
      int idx = (s0 & ~63) + ((chunk ^ (d & 7)) << 3) + off;
      *(uint2*)&Vw[((size_t)(b * NH + h) * HD + d) * SEQ + idx] = pk;
    }
  }
}

// ---------------- flash attention: 32 q/wave, register P, MFMA row-sums --------
// S^T = K.Q^T; softmax p = 2^(s-8) masked by sign-extended bit AND (exact 0);
// PV via mfma_f32_16x16x32_f16 with kk-permutation baked into Vw; row-sums via
// ones-matrix MFMA (every lane gets the complete sum for its q).
__device__ __forceinline__ void softmax8(unsigned long long mw, int sh0,
                                         const v4f* s, v8h* pf) {
  uint32_t mlo = (uint32_t)mw, mhi = (uint32_t)(mw >> 32);
  #pragma unroll
  for (int p = 0; p < 2; p++) {
    float ps[8];
    #pragma unroll
    for (int half = 0; half < 2; half++) {
      int nt = p * 2 + half;
      uint32_t w = (nt < 2) ? mlo : mhi;
      int base = sh0 + ((nt & 1) << 4);
      #pragma unroll
      for (int r = 0; r < 4; r++) {
        float e = fexp2(s[nt][r] - 8.0f);
        ps[half * 4 + r] = maskf(e, sbfe1(w, base + r));
      }
    }
    union { uint4 u; v8h h; } cc;
    cc.u.x = pack_f16(ps[0], ps[1]);
    cc.u.y = pack_f16(ps[2], ps[3]);
    cc.u.z = pack_f16(ps[4], ps[5]);
    cc.u.w = pack_f16(ps[6], ps[7]);
    pf[p] = cc.h;
  }
}

__global__ __launch_bounds__(128, 3) void flash_kernel(
    const uint16_t* __restrict__ Qg, const uint16_t* __restrict__ Kg,
    const uint16_t* __restrict__ Vg, const unsigned long long* __restrict__ Mb,
    uint16_t* __restrict__ AO)
{
  __shared__ alignas(16) uint16_t Ks[64 * 64];   // 8 KB, swizzle baked in global Kw
  __shared__ alignas(16) uint16_t Vs[64 * 64];   // 8 KB f16, perm+swz baked in Vw

  int tid = threadIdx.x, wave = tid >> 6, lane = tid & 63, lr = lane & 15, quad = lane >> 4;
  int bh = blockIdx.y;
  int b = bh / NH, h = bh - b * NH;
  int q0 = blockIdx.x * 64;
  const uint16_t* Qp = Qg + (size_t)bh * SEQ * HD;
  const uint16_t* Kp = Kg + (size_t)bh * SEQ * HD;
  const uint16_t* Vp = Vg + (size_t)bh * HD * SEQ;
  int qg0 = q0 + wave * 32 + lr;
  int qg1 = qg0 + 16;
  const unsigned long long* Mp0 = Mb + (size_t)b * 32 * SEQ + qg0;
  const unsigned long long* Mp1 = Mp0 + 16;

  int swk = lr & 7, sh0 = quad * 4;

  v8s qf0a = *(const v8s*)&Qp[(size_t)qg0 * HD + quad * 8];
  v8s qf0b = *(const v8s*)&Qp[(size_t)qg0 * HD + 32 + quad * 8];
  v8s qf1a = *(const v8s*)&Qp[(size_t)qg1 * HD + quad * 8];
  v8s qf1b = *(const v8s*)&Qp[(size_t)qg1 * HD + 32 + quad * 8];

  const uint16_t* kgl = Kp + ((size_t)(wave * 32 + (lane >> 3)) * HD + (lane & 7) * 8);
  const uint16_t* vgl = Vp + ((size_t)(wave * 32 + (lane >> 3)) * SEQ + (lane & 7) * 8);
  int lb = wave * 2048;

  // tile-invariant LDS read offsets (keep in VGPRs)
  int koff[4][2], voff[4][2];
  #pragma unroll
  for (int nt = 0; nt < 4; nt++) {
    int rowb = (nt * 16 + lr) << 6;
    koff[nt][0] = rowb + ((quad ^ swk) << 3);
    koff[nt][1] = rowb + (((quad + 4) ^ swk) << 3);
    voff[nt][0] = rowb + ((quad ^ swk) << 3);
    voff[nt][1] = rowb + (((quad + 4) ^ swk) << 3);
  }

  v8h ones;
  #pragma unroll
  for (int e = 0; e < 8; e++) ones[e] = (_Float16)1.0f;

  v4f acc0[4], acc1[4], accs0, accs1;
  v4f vz = {0.f, 0.f, 0.f, 0.f};
  #pragma unroll
  for (int dt = 0; dt < 4; dt++) { acc0[dt] = vz; acc1[dt] = vz; }
  accs0 = vz; accs1 = vz;

  unsigned long long nm0 = Mp0[0], nm1 = Mp1[0];   // tile-0 mask prefetch

  for (int k0 = 0; k0 < SEQ; k0 += 64) {
    __syncthreads();                               // prev tile's LDS reads done
    #pragma unroll
    for (int c = 0; c < 4; c++) {
      gl16(kgl + ((size_t)k0 + c * 8) * HD, &Ks[lb + c * 512]);
      gl16(vgl + k0 + (size_t)c * 8 * SEQ, &Vs[lb + c * 512]);
    }
    unsigned long long mw0 = nm0, mw1 = nm1;
    size_t nidx = (size_t)((k0 >> 6) + 1) * SEQ;   // padded row at end: safe
    nm0 = Mp0[nidx]; nm1 = Mp1[nidx];
    __syncthreads();                               // DMA complete

    // S^T = K.Q^T for both q-groups (K A-frags shared)
    v4f s0[4], s1[4];
    #pragma unroll
    for (int nt = 0; nt < 4; nt++) {
      v8s kf0 = *(const v8s*)&Ks[koff[nt][0]];
      v8s kf1 = *(const v8s*)&Ks[koff[nt][1]];
      v4f z = vz;
      z = __builtin_amdgcn_mfma_f32_16x16x32_bf16(kf0, qf0a, z, 0, 0, 0);
      z = __builtin_amdgcn_mfma_f32_16x16x32_bf16(kf1, qf0b, z, 0, 0, 0);
      s0[nt] = z;
      z = vz;
      z = __builtin_amdgcn_mfma_f32_16x16x32_bf16(kf0, qf1a, z, 0, 0, 0);
      z = __builtin_amdgcn_mfma_f32_16x16x32_bf16(kf1, qf1b, z, 0, 0, 0);
      s1[nt] = z;
    }

    v8h pf0[2], pf1[2];
    softmax8(mw0, sh0, s0, pf0);
    softmax8(mw1, sh0, s1, pf1);

    // O^T += V^T.P^T ; row-sums via ones-MFMA (full contraction per lane)
    #pragma unroll
    for (int dt = 0; dt < 4; dt++) {
      #pragma unroll
      for (int p = 0; p < 2; p++) {
        v8h vv = *(const v8h*)&Vs[voff[dt][p]];
        acc0[dt] = __builtin_amdgcn_mfma_f32_16x16x32_f16(vv, pf0[p], acc0[dt], 0, 0, 0);
        acc1[dt] = __builtin_amdgcn_mfma_f32_16x16x32_f16(vv, pf1[p], acc1[dt], 0, 0, 0);
      }
    }
    #pragma unroll
    for (int p = 0; p < 2; p++) {
      accs0 = __builtin_amdgcn_mfma_f32_16x16x32_f16(ones, pf0[p], accs0, 0, 0, 0);
      accs1 = __builtin_amdgcn_mfma_f32_16x16x32_f16(ones, pf1[p], accs1, 0, 0, 0);
    }
  }

  float ri0 = 1.0f / accs0[0];
  float ri1 = 1.0f / accs1[0];

  #pragma unroll
  for (int dt = 0; dt < 4; dt++) {
    uint2 pk;
    pk.x = pack_bf16(acc0[dt][0] * ri0, acc0[dt][1] * ri0);
    pk.y = pack_bf16(acc0[dt][2] * ri0, acc0[dt][3] * ri0);
    *(uint2*)&AO[(size_t)(b * SEQ + qg0) * DIM + h * HD + dt * 16 + sh0] = pk;
    pk.x = pack_bf16(acc1[dt][0] * ri1, acc1[dt][1] * ri1);
    pk.y = pack_bf16(acc1[dt][2] * ri1, acc1[dt][3] * ri1);
    *(uint2*)&AO[(size_t)(b * SEQ + qg1) * DIM + h * HD + dt * 16 + sh0] = pk;
  }
}

// ---------------- launch ----------------
extern "C" void kernel_launch(void* const* d_in, const int* in_sizes, int n_in,
                              void* d_out, int out_size, void* d_ws, size_t ws_size,
                              hipStream_t stream) {
  const float* from_t = (const float*)d_in[0];
  const float* to_t   = (const float*)d_in[1];
  const int*   maski  = (const int*)d_in[2];
  const float* Wq = (const float*)d_in[3];  const float* bq = (const float*)d_in[4];
  const float* Wk = (const float*)d_in[5];  const float* bk = (const float*)d_in[6];
  const float* Wv = (const float*)d_in[7];  const float* bv = (const float*)d_in[8];
  const float* Wo = (const float*)d_in[9];  const float* bo = (const float*)d_in[10];

  char* ws = (char*)d_ws;
  size_t off = 0;
  uint16_t* Xf = (uint16_t*)(ws + off); off += (size_t)MROWS * DIM * 2;
  uint16_t* Xt = (uint16_t*)(ws + off); off += (size_t)MROWS * DIM * 2;
  uint16_t* WT = (uint16_t*)(ws + off); off += (size_t)4 * DIM * DIM * 2;
  unsigned long long* Mbits = (unsigned long long*)(ws + off);
  off += (size_t)(BSZ * 32 + 1) * SEQ * 8;                              // +1 row pad (prefetch)
  uint16_t* Qw = (uint16_t*)(ws + off); off += (size_t)MROWS * DIM * 2; // [b,h,s,d] bf16
  uint16_t* Kw = (uint16_t*)(ws + off); off += (size_t)MROWS * DIM * 2; // [b,h,s,d] bf16 swz
  uint16_t* Vw = (uint16_t*)(ws + off); off += (size_t)MROWS * DIM * 2; // [b,h,d,s] f16 perm+swz
  uint16_t* AO = (uint16_t*)(ws + off); off += (size_t)MROWS * DIM * 2; // [m,768] bf16
  float* Out = (float*)d_out;

  int nx4 = MROWS * DIM / 4;
  cvt_bf16_kernel<<<2 * nx4 / 256, 256, 0, stream>>>(from_t, Xf, to_t, Xt, nx4);
  int nwords = BSZ * 32 * SEQ;
  mask_bits_kernel<<<nwords * 64 / 256, 256, 0, stream>>>(maski, Mbits, nwords);
  wtrans_kernel<<<dim3(24, 24, 4), dim3(32, 8), 0, stream>>>(Wq, Wk, Wv, Wo, WT);

  gemm_t_kernel<<<dim3(64, 6, 2), 256, 0, stream>>>(Xf, Xt, WT, AO, bq, bk, bo,
                                                    Qw, Kw, Out, 0);
  gemm_v_kernel<<<dim3(64, 6), 256, 0, stream>>>(Xt, WT, bv, Vw);
  flash_kernel<<<dim3(SEQ / 64, BSZ * NH), 128, 0, stream>>>(Qw, Kw, Vw, Mbits, AO);
  gemm_t_kernel<<<dim3(64, 6, 1), 256, 0, stream>>>(Xf, Xt, WT, AO, bq, bk, bo,
                                                    Qw, Kw, Out, 3);
}